// Round 7
// baseline (21.398 us; speedup 1.0000x reference)
//
#include <hip/hip_runtime.h>

#define N_HYP 128
#define BLOCK 1024
#define WPB 16  // waves per block, one utterance per wave

// Single fused kernel: 256 blocks x 1024 threads. Each wave computes one
// utterance's loss (same inner loop as R6). Intra-block reduce via one
// barrier, then ONE device-coherent atomicAdd per block (256 total,
// ~12ns chain each). No __threadfence, no counter, no second dispatch --
// the dependent-dispatch drain + L2 flush between k1 and k2 is gone.
__global__ __launch_bounds__(BLOCK) void margin_loss_fused(
    const float* __restrict__ scores, const int* __restrict__ werRank,
    float* __restrict__ out, int B) {
  __shared__ float s_nat[WPB][N_HYP];
  __shared__ float s_rank[WPB][N_HYP];
  __shared__ float wave_sum[WPB];

  const int tid  = threadIdx.x;
  const int lane = tid & 63;
  const int wid  = tid >> 6;
  const int u = blockIdx.x * WPB + wid;
  const bool valid = (u < B);
  const size_t base = (size_t)(valid ? u : 0) * N_HYP;

  // Two INDEPENDENT coalesced global loads (no dependent HBM hop).
  const float2 sc = *(const float2*)&scores[base + 2 * lane];
  const int2   rk = *(const int2*)&werRank[base + 2 * lane];

  *(float2*)&s_nat[wid][2 * lane] = sc;
  // In-wave LDS ordering: compiler inserts lgkmcnt before dependent reads.
  const float g0 = s_nat[wid][rk.x];  // gather within 512B row (~2-way, free)
  const float g1 = s_nat[wid][rk.y];
  *(float2*)&s_rank[wid][2 * lane] = make_float2(g0, g1);

  const float sj0 = s_rank[wid][lane];
  const float sj1 = s_rank[wid][lane + 64];

  const float4* srow = (const float4*)&s_rank[wid][0];
  float a0 = 0.f, b0 = 0.f, a1 = 0.f, b1 = 0.f;

  // k in [0,64): only the j0 term can be active (k > lane).
#pragma unroll
  for (int q = 0; q < 16; ++q) {
    const float4 sv = srow[q];
    const int k = q * 4;
    a0 += (k + 0 > lane) ? fmaxf(sv.x - sj0, 0.f) : 0.f;
    b0 += (k + 1 > lane) ? fmaxf(sv.y - sj0, 0.f) : 0.f;
    a0 += (k + 2 > lane) ? fmaxf(sv.z - sj0, 0.f) : 0.f;
    b0 += (k + 3 > lane) ? fmaxf(sv.w - sj0, 0.f) : 0.f;
  }
  // k in [64,128): j0 unconditional; j1 conditional on k-64 > lane.
#pragma unroll
  for (int q = 16; q < 32; ++q) {
    const float4 sv = srow[q];
    const int km = q * 4 - 64;
    a0 += fmaxf(sv.x - sj0, 0.f);
    b0 += fmaxf(sv.y - sj0, 0.f);
    a0 += fmaxf(sv.z - sj0, 0.f);
    b0 += fmaxf(sv.w - sj0, 0.f);
    a1 += (km + 0 > lane) ? fmaxf(sv.x - sj1, 0.f) : 0.f;
    b1 += (km + 1 > lane) ? fmaxf(sv.y - sj1, 0.f) : 0.f;
    a1 += (km + 2 > lane) ? fmaxf(sv.z - sj1, 0.f) : 0.f;
    b1 += (km + 3 > lane) ? fmaxf(sv.w - sj1, 0.f) : 0.f;
  }

  const float w0 = 1.0f / (float)(N_HYP - 1 - lane);        // j0 = lane
  const float w1 = (lane < 63) ? 1.0f / (float)(63 - lane)  // j1 = lane+64
                               : 0.0f;                      // j1 = 127: empty
  float val = (a0 + b0) * w0 + (a1 + b1) * w1;
  if (!valid) val = 0.f;

  // wave reduce -> per-wave sums in LDS -> wave 0 combines -> one atomic.
  for (int off = 32; off > 0; off >>= 1) val += __shfl_down(val, off, 64);
  if (lane == 0) wave_sum[wid] = val;
  __syncthreads();
  if (tid < 64) {
    float v = (tid < WPB) ? wave_sum[tid] : 0.f;
    for (int off = 8; off > 0; off >>= 1) v += __shfl_down(v, off, 64);
    if (tid == 0) atomicAdd(out, v);  // device-coherent, no fence needed
  }
}

extern "C" void kernel_launch(void* const* d_in, const int* in_sizes, int n_in,
                              void* d_out, int out_size, void* d_ws, size_t ws_size,
                              hipStream_t stream) {
  const float* scores  = (const float*)d_in[0];
  const int*   werRank = (const int*)d_in[2];
  float* out = (float*)d_out;
  const int B = in_sizes[0] / N_HYP;

  hipMemsetAsync(out, 0, sizeof(float), stream);
  const int nblocks = (B + WPB - 1) / WPB;  // 256 for B=4096
  margin_loss_fused<<<nblocks, BLOCK, 0, stream>>>(scores, werRank, out, B);
}

// Round 8
// 13.667 us; speedup vs baseline: 1.5657x; 1.5657x over previous
//
#include <hip/hip_runtime.h>

#define N_HYP 128
#define BLOCK 256
#define WAVES 4  // BLOCK / 64

// k1: one wave per utterance, barrier-free (R6 skeleton).
// VALU cut via max-identity: relu(s_k - s_j) = max(s_k, s_j) - s_j, so
//   sum_{k>j} relu(s_k-s_j) = [sum_k max'_k] - C*s_j,
//   max'_k = max((k>j) ? s_k : s_j, s_j)   (cndmask+max+add = 3 ops/elem,
//                                           2 ops when k>j always holds)
// The per-pair subtraction moves to a single epilogue correction.
__global__ __launch_bounds__(BLOCK) void margin_loss_k1(
    const float* __restrict__ scores, const int* __restrict__ werRank,
    float* __restrict__ partials, int B) {
  __shared__ float s_nat[WAVES][N_HYP];
  __shared__ float s_rank[WAVES][N_HYP];

  const int tid  = threadIdx.x;
  const int lane = tid & 63;
  const int wid  = tid >> 6;
  const int u = blockIdx.x * WAVES + wid;
  const bool valid = (u < B);
  const size_t base = (size_t)(valid ? u : 0) * N_HYP;

  // Two INDEPENDENT coalesced global loads (no dependent HBM hop).
  const float2 sc = *(const float2*)&scores[base + 2 * lane];
  const int2   rk = *(const int2*)&werRank[base + 2 * lane];

  *(float2*)&s_nat[wid][2 * lane] = sc;
  // In-wave LDS ordering: compiler inserts lgkmcnt before dependent reads.
  const float g0 = s_nat[wid][rk.x];  // gather within 512B row (~2-way, free)
  const float g1 = s_nat[wid][rk.y];
  *(float2*)&s_rank[wid][2 * lane] = make_float2(g0, g1);

  const float sj0 = s_rank[wid][lane];        // j0 = lane
  const float sj1 = s_rank[wid][lane + 64];   // j1 = lane + 64

  const float4* srow = (const float4*)&s_rank[wid][0];
  float a0 = 0.f, b0 = 0.f, a1 = 0.f, b1 = 0.f;  // 4 chains for ILP

  // k in [0,64): j0 term only. max'_k = max((k>lane)?s_k:sj0, sj0).
#pragma unroll
  for (int q = 0; q < 16; ++q) {
    const float4 sv = srow[q];
    const int k = q * 4;
    a0 += fmaxf((k + 0 > lane) ? sv.x : sj0, sj0);
    b0 += fmaxf((k + 1 > lane) ? sv.y : sj0, sj0);
    a0 += fmaxf((k + 2 > lane) ? sv.z : sj0, sj0);
    b0 += fmaxf((k + 3 > lane) ? sv.w : sj0, sj0);
  }
  // k in [64,128): j0 unconditional (k>j0 always); j1 conditional on k-64>lane.
#pragma unroll
  for (int q = 16; q < 32; ++q) {
    const float4 sv = srow[q];
    const int km = q * 4 - 64;
    a0 += fmaxf(sv.x, sj0);
    b0 += fmaxf(sv.y, sj0);
    a0 += fmaxf(sv.z, sj0);
    b0 += fmaxf(sv.w, sj0);
    a1 += fmaxf((km + 0 > lane) ? sv.x : sj1, sj1);
    b1 += fmaxf((km + 1 > lane) ? sv.y : sj1, sj1);
    a1 += fmaxf((km + 2 > lane) ? sv.z : sj1, sj1);
    b1 += fmaxf((km + 3 > lane) ? sv.w : sj1, sj1);
  }

  // sum_{k>j0} relu = (a0+b0) - 128*sj0 ; sum_{k>j1} relu = (a1+b1) - 64*sj1
  const float w0 = 1.0f / (float)(N_HYP - 1 - lane);
  const float w1 = (lane < 63) ? 1.0f / (float)(63 - lane) : 0.0f;
  float val = ((a0 + b0) - 128.0f * sj0) * w0 + ((a1 + b1) - 64.0f * sj1) * w1;

  for (int off = 32; off > 0; off >>= 1) val += __shfl_down(val, off, 64);
  if (lane == 0 && valid) partials[u] = val;  // per-wave partial, no barrier
}

// k2: ONE 1024-thread block; each thread loads exactly one float4 (4096
// partials) -> all loads in one round-trip; shuffle + LDS combine.
__global__ __launch_bounds__(1024) void margin_loss_k2(
    const float* __restrict__ p, int n, float* __restrict__ out) {
  const int tid = threadIdx.x;
  const int n4 = n >> 2;
  const float4* p4 = (const float4*)p;
  float v = 0.f;
  for (int i = tid; i < n4; i += 1024) {
    const float4 t = p4[i];
    v += (t.x + t.y) + (t.z + t.w);
  }
  for (int i = (n & ~3) + tid; i < n; i += 1024) v += p[i];

  for (int off = 32; off > 0; off >>= 1) v += __shfl_down(v, off, 64);
  __shared__ float ws[16];
  if ((tid & 63) == 0) ws[tid >> 6] = v;
  __syncthreads();
  if (tid < 64) {
    float w = (tid < 16) ? ws[tid] : 0.f;
    for (int off = 8; off > 0; off >>= 1) w += __shfl_down(w, off, 64);
    if (tid == 0) out[0] = w;
  }
}

extern "C" void kernel_launch(void* const* d_in, const int* in_sizes, int n_in,
                              void* d_out, int out_size, void* d_ws, size_t ws_size,
                              hipStream_t stream) {
  const float* scores  = (const float*)d_in[0];
  const int*   werRank = (const int*)d_in[2];
  float* out = (float*)d_out;
  float* partials = (float*)d_ws;
  const int B = in_sizes[0] / N_HYP;

  const int nblocks = (B + WAVES - 1) / WAVES;  // 1024 for B=4096
  margin_loss_k1<<<nblocks, BLOCK, 0, stream>>>(scores, werRank, partials, B);
  margin_loss_k2<<<1, 1024, 0, stream>>>(partials, B, out);
}